// Round 2
// baseline (198.618 us; speedup 1.0000x reference)
//
#include <hip/hip_runtime.h>

typedef float  f32x4 __attribute__((ext_vector_type(4)));
typedef short  s16x8 __attribute__((ext_vector_type(8)));

__device__ __forceinline__ float bf2f(unsigned short b){
    return __uint_as_float(((unsigned int)b) << 16);
}
__device__ __forceinline__ unsigned short f2bf(float f){
    unsigned int u = __float_as_uint(f);
    u = u + 0x7FFFu + ((u >> 16) & 1u);      // RNE
    return (unsigned short)(u >> 16);
}

// ---------------- K0a: transpose+cast W[256][256] f32 -> WT bf16 [c][k] ----------------
__global__ void k_wt(const float* __restrict__ W, unsigned short* __restrict__ WT){
    int c = blockIdx.x, k = threadIdx.x;
    WT[c*256 + k] = f2bf(W[k*256 + c]);
}

// ---------------- K0b: mask -> additive bias bf16 {0, -inf} ----------------
__global__ void k_bias(const int* __restrict__ mask, unsigned short* __restrict__ bias){
    int idx = (blockIdx.x*256 + threadIdx.x)*4;
    int4 m = *reinterpret_cast<const int4*>(mask + idx);
    unsigned int b0 = m.x ? 0u : 0xFF80u;   // bf16 -inf = 0xFF80
    unsigned int b1 = m.y ? 0u : 0xFF80u;
    unsigned int b2 = m.z ? 0u : 0xFF80u;
    unsigned int b3 = m.w ? 0u : 0xFF80u;
    uint2 o; o.x = b0 | (b1 << 16); o.y = b2 | (b3 << 16);
    *reinterpret_cast<uint2*>(bias + idx) = o;
}

// ---------------- K1: h = x @ W  (8192x256x256, MFMA 16x16x32 bf16, f32 x cast on the fly) ----
// writes hT bf16 [bh=4*b+head][d][n]  and  h32 f32 same layout (for src/dst accuracy)
__global__ __launch_bounds__(256) void k_gemm(const float* __restrict__ x,
        const unsigned short* __restrict__ WT,
        unsigned short* __restrict__ hT, float* __restrict__ h32){
    const int wave = threadIdx.x >> 6, lane = threadIdx.x & 63;
    const int q = lane >> 4, t = lane & 15;
    const int m0 = blockIdx.x*64 + wave*16;   // row tile (r = b*2048+n)
    f32x4 acc[16];
#pragma unroll
    for (int i = 0; i < 16; i++) acc[i] = (f32x4){0.f,0.f,0.f,0.f};
    const int row = m0 + t;
    for (int k = 0; k < 256; k += 32){
        int kk = k + q*8;
        const float* xp = x + row*256 + kk;
        f32x4 x0 = *reinterpret_cast<const f32x4*>(xp);
        f32x4 x1 = *reinterpret_cast<const f32x4*>(xp + 4);
        s16x8 a;
#pragma unroll
        for (int j = 0; j < 4; j++){ a[j] = (short)f2bf(x0[j]); a[j+4] = (short)f2bf(x1[j]); }
#pragma unroll
        for (int dblk = 0; dblk < 16; dblk++){
            s16x8 bfr = *reinterpret_cast<const s16x8*>(WT + (dblk*16 + t)*256 + kk);
            acc[dblk] = __builtin_amdgcn_mfma_f32_16x16x32_bf16(a, bfr, acc[dblk], 0, 0, 0);
        }
    }
#pragma unroll
    for (int dblk = 0; dblk < 16; dblk++){
        int dg = dblk*16 + t;                 // global output col in [0,256)
        int head = dg >> 6, d = dg & 63;
#pragma unroll
        for (int reg = 0; reg < 4; reg++){
            int r = m0 + q*4 + reg;           // C/D: row = quad*4+reg, col = lane&15
            int b = r >> 11, n = r & 2047;
            int o = ((b*4 + head)*64 + d)*2048 + n;
            hT[o]  = f2bf(acc[dblk][reg]);
            h32[o] = acc[dblk][reg];
        }
    }
}

// ---------------- K2: src/dst [bh][n] f32 from f32 h ----------------
__global__ void k_srcdst(const float* __restrict__ h32,
        const float* __restrict__ a_src, const float* __restrict__ a_dst,
        float* __restrict__ src, float* __restrict__ dst){
    int bh = blockIdx.x;
    int n  = blockIdx.y*256 + threadIdx.x;
    int head = bh & 3;
    float s = 0.f, dd = 0.f;
    const float* hp = h32 + bh*64*2048 + n;
#pragma unroll 8
    for (int d = 0; d < 64; d++){
        float hv = hp[d*2048];
        s  += hv * a_src[head*64 + d];
        dd += hv * a_dst[head*64 + d];
    }
    src[bh*2048 + n] = s;
    dst[bh*2048 + n] = dd;
}

// ---------------- K3: fused masked softmax + PV + ELU ----------------
// grid (16 bh, 32 i-tiles), block 256 = 4 waves, wave owns 16 rows of i.
__global__ __launch_bounds__(256) void k_attn(const unsigned short* __restrict__ hT,
        const unsigned short* __restrict__ bias, const float* __restrict__ src,
        const float* __restrict__ dst, float* __restrict__ out){
    const int bh = blockIdx.x;
    const int b = bh >> 2, head = bh & 3;
    const int wave = threadIdx.x >> 6, lane = threadIdx.x & 63;
    const int q = lane >> 4, t = lane & 15;
    const int i0 = blockIdx.y*64 + wave*16;
    const int i = i0 + t;                                  // A row of this lane
    const float vsrc = src[bh*2048 + i];
    const unsigned short* biasRow = bias + i*2048;
    const float* dstRow = dst + bh*2048;
    const unsigned short* hBase = hT + bh*64*2048 + t*2048;
    f32x4 acc0 = {0,0,0,0}, acc1 = {0,0,0,0}, acc2 = {0,0,0,0}, acc3 = {0,0,0,0};
    float S = 0.f;
#pragma unroll 2
    for (int j0 = 0; j0 < 2048; j0 += 32){
        int j = j0 + q*8;
        s16x8 h0 = *reinterpret_cast<const s16x8*>(hBase + 0*16*2048 + j);
        s16x8 h1 = *reinterpret_cast<const s16x8*>(hBase + 1*16*2048 + j);
        s16x8 h2 = *reinterpret_cast<const s16x8*>(hBase + 2*16*2048 + j);
        s16x8 h3 = *reinterpret_cast<const s16x8*>(hBase + 3*16*2048 + j);
        uint4 bu = *reinterpret_cast<const uint4*>(biasRow + j);
        f32x4 d0 = *reinterpret_cast<const f32x4*>(dstRow + j);
        f32x4 d1 = *reinterpret_cast<const f32x4*>(dstRow + j + 4);
        unsigned short bs[8];
        bs[0] = bu.x & 0xFFFFu; bs[1] = bu.x >> 16;
        bs[2] = bu.y & 0xFFFFu; bs[3] = bu.y >> 16;
        bs[4] = bu.z & 0xFFFFu; bs[5] = bu.z >> 16;
        bs[6] = bu.w & 0xFFFFu; bs[7] = bu.w >> 16;
        s16x8 afr;
#pragma unroll
        for (int jj = 0; jj < 8; jj++){
            float dv = (jj < 4) ? d0[jj] : d1[jj-4];
            float lg = vsrc + dv + bf2f(bs[jj]);
            lg = fmaxf(lg, 0.2f*lg);          // leaky relu (slope<1)
            float e = __expf(lg);             // no max-subtraction needed (|logit|<~10)
            unsigned short pb = f2bf(e);
            S += bf2f(pb);                    // S consistent with rounded p fed to MFMA
            afr[jj] = (short)pb;
        }
        acc0 = __builtin_amdgcn_mfma_f32_16x16x32_bf16(afr, h0, acc0, 0,0,0);
        acc1 = __builtin_amdgcn_mfma_f32_16x16x32_bf16(afr, h1, acc1, 0,0,0);
        acc2 = __builtin_amdgcn_mfma_f32_16x16x32_bf16(afr, h2, acc2, 0,0,0);
        acc3 = __builtin_amdgcn_mfma_f32_16x16x32_bf16(afr, h3, acc3, 0,0,0);
    }
    S += __shfl_xor(S, 16);
    S += __shfl_xor(S, 32);   // now every lane holds S for row (lane&15)
    float* orow = out + (b*2048)*256 + head*64 + t;
#pragma unroll
    for (int reg = 0; reg < 4; reg++){
        int r = q*4 + reg;                     // C/D row index within 16
        float Sr = __shfl(S, r);               // S lives at lane (row) in &15 slot
        int ig = i0 + r;
        f32x4 vals = { acc0[reg], acc1[reg], acc2[reg], acc3[reg] };
#pragma unroll
        for (int dblk = 0; dblk < 4; dblk++){
            float v = vals[dblk] / Sr;
            v = v > 0.f ? v : (__expf(v) - 1.0f);   // ELU
            orow[ig*256 + dblk*16] = v;
        }
    }
}

extern "C" void kernel_launch(void* const* d_in, const int* in_sizes, int n_in,
                              void* d_out, int out_size, void* d_ws, size_t ws_size,
                              hipStream_t stream) {
    const float* x     = (const float*)d_in[0];  // [4,2048,256] f32
    const int*   Amask = (const int*)d_in[1];    // [2048,2048] int32
    const float* W     = (const float*)d_in[2];  // [256,256] f32
    const float* a_src = (const float*)d_in[3];  // [4,64] f32
    const float* a_dst = (const float*)d_in[4];  // [4,64] f32
    float* out = (float*)d_out;                  // [4,2048,256] f32

    char* ws = (char*)d_ws;
    unsigned short* bias = (unsigned short*)(ws);                        // 8 MB
    unsigned short* hT   = (unsigned short*)(ws + (8u<<20));             // 4 MB
    float*          h32  = (float*)(ws + (12u<<20));                     // 8 MB
    unsigned short* WT   = (unsigned short*)(ws + (20u<<20));            // 128 KB
    float*          src  = (float*)(ws + (20u<<20) + (256u<<10));        // 128 KB
    float*          dst  = (float*)(ws + (20u<<20) + (512u<<10));        // 128 KB

    hipLaunchKernelGGL(k_wt,     dim3(256),     dim3(256), 0, stream, W, WT);
    hipLaunchKernelGGL(k_bias,   dim3(4096),    dim3(256), 0, stream, Amask, bias);
    hipLaunchKernelGGL(k_gemm,   dim3(128),     dim3(256), 0, stream, x, WT, hT, h32);
    hipLaunchKernelGGL(k_srcdst, dim3(16, 8),   dim3(256), 0, stream, h32, a_src, a_dst, src, dst);
    hipLaunchKernelGGL(k_attn,   dim3(16, 32),  dim3(256), 0, stream, hT, bias, src, dst, out);
}

// Round 3
// 173.908 us; speedup vs baseline: 1.1421x; 1.1421x over previous
//
#include <hip/hip_runtime.h>

typedef float  f32x4 __attribute__((ext_vector_type(4)));
typedef short  s16x8 __attribute__((ext_vector_type(8)));

__device__ __forceinline__ unsigned short f2bf(float f){
    unsigned int u = __float_as_uint(f);
    u = u + 0x7FFFu + ((u >> 16) & 1u);      // RNE
    return (unsigned short)(u >> 16);
}

// ---------------- K0a: transpose+cast W[256][256] f32 -> WT bf16 [c][k] ----------------
__global__ void k_wt(const float* __restrict__ W, unsigned short* __restrict__ WT){
    int c = blockIdx.x, k = threadIdx.x;
    WT[c*256 + k] = f2bf(W[k*256 + c]);
}

// ---------------- K0b: mask -> additive bias bf16 {0, -inf} ----------------
__global__ void k_bias(const int* __restrict__ mask, unsigned short* __restrict__ bias){
    int idx = (blockIdx.x*256 + threadIdx.x)*4;
    int4 m = *reinterpret_cast<const int4*>(mask + idx);
    unsigned int b0 = m.x ? 0u : 0xFF80u;   // bf16 -inf = 0xFF80
    unsigned int b1 = m.y ? 0u : 0xFF80u;
    unsigned int b2 = m.z ? 0u : 0xFF80u;
    unsigned int b3 = m.w ? 0u : 0xFF80u;
    uint2 o; o.x = b0 | (b1 << 16); o.y = b2 | (b3 << 16);
    *reinterpret_cast<uint2*>(bias + idx) = o;
}

// ---------------- K1: h = x @ W, fused src/dst ----------------
// grid (128 row-tiles, 4 heads). Writes hT bf16 [bh][d][n], src/dst f32 [bh][n].
__global__ __launch_bounds__(256) void k_gemm(const float* __restrict__ x,
        const unsigned short* __restrict__ WT,
        const float* __restrict__ a_src, const float* __restrict__ a_dst,
        unsigned short* __restrict__ hT, float* __restrict__ src, float* __restrict__ dst){
    const int wave = threadIdx.x >> 6, lane = threadIdx.x & 63;
    const int q = lane >> 4, t = lane & 15;
    const int m0 = blockIdx.x*64 + wave*16;   // row tile (r = b*2048+n)
    const int head = blockIdx.y;
    f32x4 acc[4] = {{0,0,0,0},{0,0,0,0},{0,0,0,0},{0,0,0,0}};
    const int row = m0 + t;
    for (int k = 0; k < 256; k += 32){
        int kk = k + q*8;
        const float* xp = x + row*256 + kk;
        f32x4 x0 = *reinterpret_cast<const f32x4*>(xp);
        f32x4 x1 = *reinterpret_cast<const f32x4*>(xp + 4);
        s16x8 a;
#pragma unroll
        for (int j = 0; j < 4; j++){ a[j] = (short)f2bf(x0[j]); a[j+4] = (short)f2bf(x1[j]); }
#pragma unroll
        for (int dblk = 0; dblk < 4; dblk++){
            s16x8 bfr = *reinterpret_cast<const s16x8*>(WT + (head*64 + dblk*16 + t)*256 + kk);
            acc[dblk] = __builtin_amdgcn_mfma_f32_16x16x32_bf16(a, bfr, acc[dblk], 0, 0, 0);
        }
    }
    const int b = m0 >> 11;                   // block never straddles batch boundary
    const int bh = b*4 + head;
    // fused src/dst: per row r, dot over 64 cols (cols t+16*dblk on this lane)
    float as_[4], ad_[4];
#pragma unroll
    for (int dblk = 0; dblk < 4; dblk++){
        as_[dblk] = a_src[head*64 + dblk*16 + t];
        ad_[dblk] = a_dst[head*64 + dblk*16 + t];
    }
#pragma unroll
    for (int reg = 0; reg < 4; reg++){
        float sv = acc[0][reg]*as_[0] + acc[1][reg]*as_[1] + acc[2][reg]*as_[2] + acc[3][reg]*as_[3];
        float dv = acc[0][reg]*ad_[0] + acc[1][reg]*ad_[1] + acc[2][reg]*ad_[2] + acc[3][reg]*ad_[3];
#pragma unroll
        for (int off = 1; off < 16; off <<= 1){
            sv += __shfl_xor(sv, off);
            dv += __shfl_xor(dv, off);
        }
        if (t == 0){
            int n = (m0 + q*4 + reg) & 2047;
            src[bh*2048 + n] = sv;
            dst[bh*2048 + n] = dv;
        }
    }
    // hT store (bf16, transposed [d][n])
#pragma unroll
    for (int dblk = 0; dblk < 4; dblk++){
        int d = dblk*16 + t;
#pragma unroll
        for (int reg = 0; reg < 4; reg++){
            int n = (m0 + q*4 + reg) & 2047;
            hT[(bh*64 + d)*2048 + n] = f2bf(acc[dblk][reg]);
        }
    }
}

// ---------------- K2: fused masked softmax + PV + ELU, j split across waves ----------------
// grid (16 bh, 128 i-tiles of 16 rows), block 256 = 4 waves, wave = 512-wide j-chunk.
__global__ __launch_bounds__(256, 8) void k_attn(const unsigned short* __restrict__ hT,
        const unsigned short* __restrict__ bias, const float* __restrict__ src,
        const float* __restrict__ dst, float* __restrict__ out){
    __shared__ float accL[4][16][64];
    __shared__ float Sl[4][16];
    const int bh = blockIdx.x;
    const int b = bh >> 2, head = bh & 3;
    const int wave = threadIdx.x >> 6, lane = threadIdx.x & 63;
    const int q = lane >> 4, t = lane & 15;
    const int i0 = blockIdx.y*16;
    const int i = i0 + t;                                  // A row of this lane
    const float vsrc = src[bh*2048 + i];
    const unsigned short* biasRow = bias + i*2048 + wave*512;
    const float* dstRow = dst + bh*2048 + wave*512;
    const unsigned short* hBase = hT + bh*64*2048 + t*2048 + wave*512;
    f32x4 acc0 = {0,0,0,0}, acc1 = {0,0,0,0}, acc2 = {0,0,0,0}, acc3 = {0,0,0,0};
    float S = 0.f;
    for (int jt = 0; jt < 512; jt += 32){
        int j = jt + q*8;
        s16x8 h0 = *reinterpret_cast<const s16x8*>(hBase + 0*16*2048 + j);
        s16x8 h1 = *reinterpret_cast<const s16x8*>(hBase + 1*16*2048 + j);
        s16x8 h2 = *reinterpret_cast<const s16x8*>(hBase + 2*16*2048 + j);
        s16x8 h3 = *reinterpret_cast<const s16x8*>(hBase + 3*16*2048 + j);
        uint4 bu = *reinterpret_cast<const uint4*>(biasRow + j);
        f32x4 d0 = *reinterpret_cast<const f32x4*>(dstRow + j);
        f32x4 d1 = *reinterpret_cast<const f32x4*>(dstRow + j + 4);
        // logits -> exp, truncation-packed to bf16 (1 v_perm per 2 elems)
        float e[8];
#pragma unroll
        for (int jj = 0; jj < 8; jj++){
            float bb = __uint_as_float(((jj&1) ? ((&bu.x)[jj>>1] & 0xFFFF0000u)
                                               : ((&bu.x)[jj>>1] << 16)));
            float dv = (jj < 4) ? d0[jj] : d1[jj-4];
            float lg = vsrc + dv + bb;
            lg = fmaxf(lg, 0.2f*lg);          // leaky relu
            e[jj] = __expf(lg);               // bounded logits: no max-subtraction
        }
        union { uint4 u; s16x8 s; } pk;
        pk.u.x = __builtin_amdgcn_perm(__float_as_uint(e[1]), __float_as_uint(e[0]), 0x07060302u);
        pk.u.y = __builtin_amdgcn_perm(__float_as_uint(e[3]), __float_as_uint(e[2]), 0x07060302u);
        pk.u.z = __builtin_amdgcn_perm(__float_as_uint(e[5]), __float_as_uint(e[4]), 0x07060302u);
        pk.u.w = __builtin_amdgcn_perm(__float_as_uint(e[7]), __float_as_uint(e[6]), 0x07060302u);
        // S from the truncated values (consistent with MFMA numerator)
        S += __uint_as_float(pk.u.x << 16) + __uint_as_float(pk.u.x & 0xFFFF0000u);
        S += __uint_as_float(pk.u.y << 16) + __uint_as_float(pk.u.y & 0xFFFF0000u);
        S += __uint_as_float(pk.u.z << 16) + __uint_as_float(pk.u.z & 0xFFFF0000u);
        S += __uint_as_float(pk.u.w << 16) + __uint_as_float(pk.u.w & 0xFFFF0000u);
        acc0 = __builtin_amdgcn_mfma_f32_16x16x32_bf16(pk.s, h0, acc0, 0,0,0);
        acc1 = __builtin_amdgcn_mfma_f32_16x16x32_bf16(pk.s, h1, acc1, 0,0,0);
        acc2 = __builtin_amdgcn_mfma_f32_16x16x32_bf16(pk.s, h2, acc2, 0,0,0);
        acc3 = __builtin_amdgcn_mfma_f32_16x16x32_bf16(pk.s, h3, acc3, 0,0,0);
    }
    S += __shfl_xor(S, 16);
    S += __shfl_xor(S, 32);   // every lane now holds chunk-sum for its row t
    // deposit partials in LDS
#pragma unroll
    for (int reg = 0; reg < 4; reg++){
        int r = q*4 + reg;
        accL[wave][r][ 0 + t] = acc0[reg];
        accL[wave][r][16 + t] = acc1[reg];
        accL[wave][r][32 + t] = acc2[reg];
        accL[wave][r][48 + t] = acc3[reg];
    }
    if (q == 0) Sl[wave][t] = S;
    __syncthreads();
    // combine: 256 threads x 4 floats = 16 rows x 64 d
    const int tid = threadIdx.x;
    const int row = tid >> 4;
    const int d   = (tid & 15) * 4;
    f32x4 v0 = *reinterpret_cast<const f32x4*>(&accL[0][row][d]);
    f32x4 v1 = *reinterpret_cast<const f32x4*>(&accL[1][row][d]);
    f32x4 v2 = *reinterpret_cast<const f32x4*>(&accL[2][row][d]);
    f32x4 v3 = *reinterpret_cast<const f32x4*>(&accL[3][row][d]);
    float Ssum = Sl[0][row] + Sl[1][row] + Sl[2][row] + Sl[3][row];
    float rS = 1.0f / Ssum;
    f32x4 v;
#pragma unroll
    for (int c = 0; c < 4; c++){
        float vv = (v0[c] + v1[c] + v2[c] + v3[c]) * rS;
        v[c] = vv > 0.f ? vv : (__expf(vv) - 1.0f);   // ELU
    }
    *reinterpret_cast<f32x4*>(out + (b*2048 + i0 + row)*256 + head*64 + d) = v;
}

extern "C" void kernel_launch(void* const* d_in, const int* in_sizes, int n_in,
                              void* d_out, int out_size, void* d_ws, size_t ws_size,
                              hipStream_t stream) {
    const float* x     = (const float*)d_in[0];  // [4,2048,256] f32
    const int*   Amask = (const int*)d_in[1];    // [2048,2048] int32
    const float* W     = (const float*)d_in[2];  // [256,256] f32
    const float* a_src = (const float*)d_in[3];  // [4,64] f32
    const float* a_dst = (const float*)d_in[4];  // [4,64] f32
    float* out = (float*)d_out;                  // [4,2048,256] f32

    char* ws = (char*)d_ws;
    unsigned short* bias = (unsigned short*)(ws);                        // 8 MB
    unsigned short* hT   = (unsigned short*)(ws + (8u<<20));             // 4 MB
    unsigned short* WT   = (unsigned short*)(ws + (12u<<20));            // 128 KB
    float*          src  = (float*)(ws + (12u<<20) + (128u<<10));        // 128 KB
    float*          dst  = (float*)(ws + (12u<<20) + (256u<<10));        // 128 KB

    hipLaunchKernelGGL(k_wt,   dim3(256),      dim3(256), 0, stream, W, WT);
    hipLaunchKernelGGL(k_bias, dim3(4096),     dim3(256), 0, stream, Amask, bias);
    hipLaunchKernelGGL(k_gemm, dim3(128, 4),   dim3(256), 0, stream, x, WT, a_src, a_dst, hT, src, dst);
    hipLaunchKernelGGL(k_attn, dim3(16, 128),  dim3(256), 0, stream, hT, bias, src, dst, out);
}

// Round 5
// 131.190 us; speedup vs baseline: 1.5140x; 1.3256x over previous
//
#include <hip/hip_runtime.h>

typedef float  f32x4 __attribute__((ext_vector_type(4)));
typedef short  s16x8 __attribute__((ext_vector_type(8)));

__device__ __forceinline__ unsigned short f2bf(float f){
    unsigned int u = __float_as_uint(f);
    u = u + 0x7FFFu + ((u >> 16) & 1u);      // RNE
    return (unsigned short)(u >> 16);
}

// ---------------- K0a: transpose+cast W[256][256] f32 -> WT bf16 [c][k] ----------------
__global__ void k_wt(const float* __restrict__ W, unsigned short* __restrict__ WT){
    int c = blockIdx.x, k = threadIdx.x;
    WT[c*256 + k] = f2bf(W[k*256 + c]);
}

// ---------------- K0b: mask -> bitmask (1 bit per entry), row-major u64 chunks ----------
__global__ void k_bits(const int* __restrict__ mask, unsigned long long* __restrict__ bits64){
    int i = blockIdx.x;
    int wave = threadIdx.x >> 6, lane = threadIdx.x & 63;
    for (int c = wave; c < 32; c += 4){
        int v = mask[i*2048 + c*64 + lane];
        unsigned long long b = __ballot(v != 0);
        if (lane == 0) bits64[i*32 + c] = b;
    }
}

// ---------------- K1: h = x @ W, fused src/dst (R3-validated math; only store re-indexed) --
// grid (128 row-tiles, 4 heads). Writes hTt bf16 [bh][jb=n/16][d<64][jj=n%16], src/dst f32.
__global__ __launch_bounds__(256) void k_gemm(const float* __restrict__ x,
        const unsigned short* __restrict__ WT,
        const float* __restrict__ a_src, const float* __restrict__ a_dst,
        unsigned short* __restrict__ hTt, float* __restrict__ src, float* __restrict__ dst){
    const int wave = threadIdx.x >> 6, lane = threadIdx.x & 63;
    const int q = lane >> 4, t = lane & 15;
    const int m0 = blockIdx.x*64 + wave*16;   // row tile (r = b*2048+n)
    const int head = blockIdx.y;
    f32x4 acc[4] = {{0,0,0,0},{0,0,0,0},{0,0,0,0},{0,0,0,0}};
    const int row = m0 + t;
    for (int k = 0; k < 256; k += 32){
        int kk = k + q*8;
        const float* xp = x + row*256 + kk;
        f32x4 x0 = *reinterpret_cast<const f32x4*>(xp);
        f32x4 x1 = *reinterpret_cast<const f32x4*>(xp + 4);
        s16x8 a;
#pragma unroll
        for (int j = 0; j < 4; j++){ a[j] = (short)f2bf(x0[j]); a[j+4] = (short)f2bf(x1[j]); }
#pragma unroll
        for (int dblk = 0; dblk < 4; dblk++){
            s16x8 bfr = *reinterpret_cast<const s16x8*>(WT + (head*64 + dblk*16 + t)*256 + kk);
            acc[dblk] = __builtin_amdgcn_mfma_f32_16x16x32_bf16(a, bfr, acc[dblk], 0, 0, 0);
        }
    }
    const int b = m0 >> 11;                   // tile never straddles batch boundary
    const int bh = b*4 + head;
    const int jb = (m0 & 2047) >> 4;
    // fused src/dst (R3-validated, unchanged)
    float as_[4], ad_[4];
#pragma unroll
    for (int dblk = 0; dblk < 4; dblk++){
        as_[dblk] = a_src[head*64 + dblk*16 + t];
        ad_[dblk] = a_dst[head*64 + dblk*16 + t];
    }
#pragma unroll
    for (int reg = 0; reg < 4; reg++){
        float sv = acc[0][reg]*as_[0] + acc[1][reg]*as_[1] + acc[2][reg]*as_[2] + acc[3][reg]*as_[3];
        float dv = acc[0][reg]*ad_[0] + acc[1][reg]*ad_[1] + acc[2][reg]*ad_[2] + acc[3][reg]*ad_[3];
#pragma unroll
        for (int off = 1; off < 16; off <<= 1){
            sv += __shfl_xor(sv, off);
            dv += __shfl_xor(dv, off);
        }
        if (t == 0){
            int n = (m0 + q*4 + reg) & 2047;
            src[bh*2048 + n] = sv;
            dst[bh*2048 + n] = dv;
        }
    }
    // hTt store: same values as R3's hT store, re-indexed to [bh][jb][d][jj]
#pragma unroll
    for (int dblk = 0; dblk < 4; dblk++){
        int d = dblk*16 + t;
#pragma unroll
        for (int reg = 0; reg < 4; reg++){
            int jj = q*4 + reg;               // n = m0 + jj
            hTt[((bh*128 + jb)*64 + d)*16 + jj] = f2bf(acc[dblk][reg]);
        }
    }
}

// ---------------- K2: fused masked softmax + PV + ELU (R3 structure, new V/mask reads) ---
// grid (16 bh, 128 i-tiles of 16 rows), block 256 = 4 waves, wave = 512-wide j-chunk.
__global__ __launch_bounds__(256, 8) void k_attn(const unsigned short* __restrict__ hTt,
        const unsigned int* __restrict__ bits, const float* __restrict__ src,
        const float* __restrict__ dst, float* __restrict__ out){
    __shared__ float accL[4][16][64];
    __shared__ float Sl[4][16];
    const int bh = blockIdx.x;
    const int b = bh >> 2, head = bh & 3;
    const int wave = threadIdx.x >> 6, lane = threadIdx.x & 63;
    const int q = lane >> 4, t = lane & 15, q8 = q*8;
    const int i0 = blockIdx.y*16;
    const int i = i0 + t;                                  // A row of this lane
    const float NEGINF = -__builtin_inff();
    const float vsrc = src[bh*2048 + i];
    const unsigned int* bR = bits + i*64 + wave*16;        // u32 word covers 32 j-cols
    const float* dR = dst + bh*2048 + wave*512 + q8;
    const unsigned short* vB = hTt + bh*131072 + wave*32768 + (q>>1)*1024 + (q&1)*8 + t*16;
    f32x4 acc0 = {0,0,0,0}, acc1 = {0,0,0,0}, acc2 = {0,0,0,0}, acc3 = {0,0,0,0};
    float S = 0.f;
    for (int it = 0; it < 16; ++it){
        const unsigned short* vp = vB + it*2048;
        s16x8 h0 = *reinterpret_cast<const s16x8*>(vp);
        s16x8 h1 = *reinterpret_cast<const s16x8*>(vp + 256);
        s16x8 h2 = *reinterpret_cast<const s16x8*>(vp + 512);
        s16x8 h3 = *reinterpret_cast<const s16x8*>(vp + 768);
        unsigned int bs = bR[it] >> q8;
        f32x4 d0 = *reinterpret_cast<const f32x4*>(dR + it*32);
        f32x4 d1 = *reinterpret_cast<const f32x4*>(dR + it*32 + 4);
        float e[8];
#pragma unroll
        for (int jj = 0; jj < 8; jj++){
            float dvv = (jj < 4) ? d0[jj] : d1[jj-4];
            float lg = vsrc + dvv;
            lg = fmaxf(lg, 0.2f*lg);                       // leaky relu
            lg = ((bs >> jj) & 1u) ? lg : NEGINF;          // mask -> exp = 0
            e[jj] = __expf(lg);                            // bounded logits: no max-sub
        }
        union { unsigned int u[4]; s16x8 s; } pk;
#pragma unroll
        for (int p = 0; p < 4; p++)
            pk.u[p] = __builtin_amdgcn_perm(__float_as_uint(e[2*p+1]), __float_as_uint(e[2*p]), 0x07060302u);
        // S from the truncated values (consistent with MFMA numerator) — R3-validated
        S += __uint_as_float(pk.u[0] << 16) + __uint_as_float(pk.u[0] & 0xFFFF0000u);
        S += __uint_as_float(pk.u[1] << 16) + __uint_as_float(pk.u[1] & 0xFFFF0000u);
        S += __uint_as_float(pk.u[2] << 16) + __uint_as_float(pk.u[2] & 0xFFFF0000u);
        S += __uint_as_float(pk.u[3] << 16) + __uint_as_float(pk.u[3] & 0xFFFF0000u);
        acc0 = __builtin_amdgcn_mfma_f32_16x16x32_bf16(pk.s, h0, acc0, 0,0,0);
        acc1 = __builtin_amdgcn_mfma_f32_16x16x32_bf16(pk.s, h1, acc1, 0,0,0);
        acc2 = __builtin_amdgcn_mfma_f32_16x16x32_bf16(pk.s, h2, acc2, 0,0,0);
        acc3 = __builtin_amdgcn_mfma_f32_16x16x32_bf16(pk.s, h3, acc3, 0,0,0);
    }
    S += __shfl_xor(S, 16);
    S += __shfl_xor(S, 32);   // every lane now holds chunk-sum for its row t
#pragma unroll
    for (int reg = 0; reg < 4; reg++){
        int r = q*4 + reg;
        accL[wave][r][ 0 + t] = acc0[reg];
        accL[wave][r][16 + t] = acc1[reg];
        accL[wave][r][32 + t] = acc2[reg];
        accL[wave][r][48 + t] = acc3[reg];
    }
    if (q == 0) Sl[wave][t] = S;
    __syncthreads();
    // combine: 256 threads x 4 floats = 16 rows x 64 d  (R3-validated)
    const int tid = threadIdx.x;
    const int row = tid >> 4;
    const int d   = (tid & 15) * 4;
    f32x4 v0 = *reinterpret_cast<const f32x4*>(&accL[0][row][d]);
    f32x4 v1 = *reinterpret_cast<const f32x4*>(&accL[1][row][d]);
    f32x4 v2 = *reinterpret_cast<const f32x4*>(&accL[2][row][d]);
    f32x4 v3 = *reinterpret_cast<const f32x4*>(&accL[3][row][d]);
    float Ssum = Sl[0][row] + Sl[1][row] + Sl[2][row] + Sl[3][row];
    float rS = 1.0f / Ssum;
    f32x4 v;
#pragma unroll
    for (int c = 0; c < 4; c++){
        float vv = (v0[c] + v1[c] + v2[c] + v3[c]) * rS;
        v[c] = vv > 0.f ? vv : (__expf(vv) - 1.0f);   // ELU
    }
    *reinterpret_cast<f32x4*>(out + (b*2048 + i0 + row)*256 + head*64 + d) = v;
}

extern "C" void kernel_launch(void* const* d_in, const int* in_sizes, int n_in,
                              void* d_out, int out_size, void* d_ws, size_t ws_size,
                              hipStream_t stream) {
    const float* x     = (const float*)d_in[0];  // [4,2048,256] f32
    const int*   Amask = (const int*)d_in[1];    // [2048,2048] int32
    const float* W     = (const float*)d_in[2];  // [256,256] f32
    const float* a_src = (const float*)d_in[3];  // [4,64] f32
    const float* a_dst = (const float*)d_in[4];  // [4,64] f32
    float* out = (float*)d_out;                  // [4,2048,256] f32

    char* ws = (char*)d_ws;
    unsigned short*     hTt  = (unsigned short*)(ws);                    // 4 MB
    unsigned long long* bits = (unsigned long long*)(ws + (4u<<20));     // 512 KB
    unsigned short*     WT   = (unsigned short*)(ws + (4u<<20) + (512u<<10)); // 128 KB
    float*              src  = (float*)(ws + (4u<<20) + (640u<<10));     // 128 KB
    float*              dst  = (float*)(ws + (4u<<20) + (768u<<10));     // 128 KB

    hipLaunchKernelGGL(k_wt,   dim3(256),      dim3(256), 0, stream, W, WT);
    hipLaunchKernelGGL(k_bits, dim3(2048),     dim3(256), 0, stream, Amask, bits);
    hipLaunchKernelGGL(k_gemm, dim3(128, 4),   dim3(256), 0, stream, x, WT, a_src, a_dst, hTt, src, dst);
    hipLaunchKernelGGL(k_attn, dim3(16, 128),  dim3(256), 0, stream, hTt, (const unsigned int*)bits, src, dst, out);
}